// Round 3
// baseline (109.901 us; speedup 1.0000x reference)
//
#include <hip/hip_runtime.h>

typedef __bf16 bf16_t;
typedef __bf16 bf16x8 __attribute__((ext_vector_type(8)));
typedef float  f32x4  __attribute__((ext_vector_type(4)));

#define Ldim 2048
#define Ddim 256
#define MROWS 64

__device__ inline unsigned int bfbits(float f) {
    bf16_t b = (bf16_t)f;
    unsigned short u;
    __builtin_memcpy(&u, &b, 2);
    return (unsigned int)u;
}

__global__ __launch_bounds__(256, 1)
void rnn_kernel(const float* __restrict__ x,
                const float* __restrict__ wgt,
                const float* __restrict__ win,
                const float* __restrict__ bias,
                const float* __restrict__ tau,
                float* __restrict__ out)
{
    // Double-buffered h A-fragment store, bit-permuted conflict-free layout.
    // chunk (mt,kt) base = mt*8192 + kt*1024; element (m=4q+r, k'=8qp+j) at
    // byte r*256 + qp*64 + q*16 + j*2.
    __shared__ char hb[2 * 32768];

    const int tid = threadIdx.x;
    const int w   = tid >> 6;   // wave: owns n-cols [64w, 64w+64)
    const int ln  = tid & 63;
    const int c   = ln & 15;
    const int q   = ln >> 4;
    const int blk = blockIdx.x;
    const int bb  = blk >> 5;             // batch
    const int l0  = (blk & 31) * MROWS;   // first output row within batch

    int   ncol[4];
    float itau[4];
#pragma unroll
    for (int nl = 0; nl < 4; ++nl) {
        ncol[nl] = (4 * w + nl) * 16 + c;
        itau[nl] = 1.0f / tau[ncol[nl]];
    }

    // ---------- phase 1: au = X_window @ W_in + bias; also gather W frags ----------
    f32x4 au[5][4];
#pragma unroll
    for (int nl = 0; nl < 4; ++nl) {
        float bv = bias[ncol[nl]];
#pragma unroll
        for (int mt = 0; mt < 5; ++mt) {
            f32x4 t = {bv, bv, bv, bv};
            au[mt][nl] = t;
        }
    }

    const float* xb = x + (long)bb * (Ldim * Ddim);
    const f32x4 zf = {0.f, 0.f, 0.f, 0.f};

    auto loadX = [&](f32x4 (&buf)[5][2], int kt) {
#pragma unroll
        for (int mt = 0; mt < 5; ++mt) {
            int  lrow = l0 - 7 + mt * 16 + c;
            bool ok   = (lrow >= 0) && (lrow < Ldim);
            const f32x4* p = (const f32x4*)(xb + (long)lrow * Ddim + kt * 32 + q * 8);
            buf[mt][0] = ok ? p[0] : zf;
            buf[mt][1] = ok ? p[1] : zf;
        }
    };
    // direct-global fragment gather: wb[nl][j] = src[(kt*32+q*8+j)][16*(4w+nl)+c]
    auto loadWF = [&](bf16x8 (&wb)[4], const float* __restrict__ src, int kt) {
        const float* base = src + (long)(kt * 32 + q * 8) * Ddim + c;
#pragma unroll
        for (int nl = 0; nl < 4; ++nl) {
            const float* p = base + (4 * w + nl) * 16;
#pragma unroll
            for (int j = 0; j < 8; ++j)
                wb[nl][j] = (bf16_t)p[(long)j * Ddim];
        }
    };
    auto step1 = [&](const f32x4 (&buf)[5][2], const bf16x8 (&wb)[4]) {
        bf16x8 aF[5];
#pragma unroll
        for (int mt = 0; mt < 5; ++mt)
#pragma unroll
            for (int jj = 0; jj < 4; ++jj) {
                aF[mt][jj]     = (bf16_t)buf[mt][0][jj];
                aF[mt][jj + 4] = (bf16_t)buf[mt][1][jj];
            }
#pragma unroll
        for (int nl = 0; nl < 4; ++nl)
#pragma unroll
            for (int mt = 0; mt < 5; ++mt)
                au[mt][nl] = __builtin_amdgcn_mfma_f32_16x16x32_bf16(
                    aF[mt], wb[nl], au[mt][nl], 0, 0, 0);
    };

    bf16x8 bfr[8][4];   // W (recurrent) B-fragments, register resident
    {
        f32x4  x0[5][2], x1[5][2];
        bf16x8 w0[4], w1[4];
        loadX(x0, 0); loadWF(w0, win, 0);
#pragma unroll
        for (int kk = 0; kk < 4; ++kk) {
            loadX(x1, 2 * kk + 1); loadWF(w1, win, 2 * kk + 1);
            loadWF(bfr[2 * kk], wgt, 2 * kk);          // recurrent W, used in phase 2
            step1(x0, w0);
            if (kk < 3) { loadX(x0, 2 * kk + 2); loadWF(w0, win, 2 * kk + 2); }
            loadWF(bfr[2 * kk + 1], wgt, 2 * kk + 1);
            step1(x1, w1);
        }
    }

    // ---------- phase 2: 8-step recurrence ----------
    // packed-scatter byte offsets (t-invariant): pair columns (kk&~1, kk|1)
    int offnp[4];
#pragma unroll
    for (int nl = 0; nl < 4; ++nl) {
        int kk2 = ncol[nl] & ~1;
        offnp[nl] = (kk2 >> 5) * 1024 + ((kk2 >> 3) & 3) * 64 + q * 16 + (kk2 & 7) * 2;
    }
    const int codd   = c & 1;
    const int permln = (((ln & 3) << 4) | ((ln >> 4) << 2) | ((ln >> 2) & 3)) * 16;
    const int sl     = (ln + 16) & 63;

    f32x4 h[4][4];   // h in C-layout fp32
#pragma unroll
    for (int mt = 0; mt < 4; ++mt)
#pragma unroll
        for (int nl = 0; nl < 4; ++nl)
#pragma unroll
            for (int r = 0; r < 4; ++r)
                h[mt][nl][r] = itau[nl] * fmaxf(au[mt][nl][r], 0.0f);

#pragma unroll 1
    for (int t = 1; t < 8; ++t) {
        char* hbw = hb + ((t - 1) & 1) * 32768;
        // shift au down one row: au[r] <- au[r+1], au[3] <- next quad/tile row 0
#pragma unroll
        for (int nl = 0; nl < 4; ++nl) {
            float a[5];
#pragma unroll
            for (int mt = 0; mt < 5; ++mt) a[mt] = __shfl(au[mt][nl][0], sl);
#pragma unroll
            for (int mt = 0; mt < 5; ++mt) {
                float n3 = (q < 3) ? a[mt] : (mt < 4 ? a[mt + 1] : a[mt]);
                f32x4 o = au[mt][nl];
                f32x4 s = {o[1], o[2], o[3], n3};
                au[mt][nl] = s;
            }
        }
        // packed scatter: DPP pairs adjacent columns -> 32 ds_write_b32, 2-way banks
#pragma unroll
        for (int mt = 0; mt < 4; ++mt)
#pragma unroll
            for (int nl = 0; nl < 4; ++nl) {
                unsigned int P[4];
#pragma unroll
                for (int r = 0; r < 4; ++r) {
                    unsigned int own = bfbits(h[mt][nl][r]);
                    unsigned int par = (unsigned int)__builtin_amdgcn_mov_dpp(
                        (int)own, 0xB1, 0xF, 0xF, true);  // quad_perm(1,0,3,2)
                    P[r] = codd ? (par | (own << 16)) : (own | (par << 16));
                }
                unsigned int v0 = codd ? P[1] : P[0];   // row r = 0+codd
                unsigned int v1 = codd ? P[3] : P[2];   // row r = 2+codd
                char* bp = hbw + mt * 8192 + codd * 256 + offnp[nl];
                *(unsigned int*)bp         = v0;
                *(unsigned int*)(bp + 512) = v1;
            }
        __syncthreads();   // single barrier per step (double-buffered hbuf)
        f32x4 acc[4][4];
#pragma unroll
        for (int kt = 0; kt < 8; ++kt) {
            bf16x8 aF[4];
#pragma unroll
            for (int mt = 0; mt < 4; ++mt)
                aF[mt] = *(const bf16x8*)(hbw + (mt * 8 + kt) * 1024 + permln);
#pragma unroll
            for (int nl = 0; nl < 4; ++nl)
#pragma unroll
                for (int mt = 0; mt < 4; ++mt)
                    acc[mt][nl] = __builtin_amdgcn_mfma_f32_16x16x32_bf16(
                        aF[mt], bfr[kt][nl],
                        (kt == 0) ? au[mt][nl] : acc[mt][nl], 0, 0, 0);
        }
        // h <- h + itau * (relu(hW + u) - h)
#pragma unroll
        for (int mt = 0; mt < 4; ++mt)
#pragma unroll
            for (int nl = 0; nl < 4; ++nl)
#pragma unroll
                for (int r = 0; r < 4; ++r) {
                    float hh = h[mt][nl][r];
                    float s  = fmaxf(acc[mt][nl][r], 0.0f);
                    h[mt][nl][r] = hh + itau[nl] * (s - hh);
                }
    }

    // ---------- epilogue ----------
    float* ob = out + ((long)bb * Ldim + l0) * Ddim;
#pragma unroll
    for (int mt = 0; mt < 4; ++mt)
#pragma unroll
        for (int nl = 0; nl < 4; ++nl)
#pragma unroll
            for (int r = 0; r < 4; ++r)
                ob[(mt * 16 + 4 * q + r) * Ddim + ncol[nl]] = h[mt][nl][r];
}

extern "C" void kernel_launch(void* const* d_in, const int* in_sizes, int n_in,
                              void* d_out, int out_size, void* d_ws, size_t ws_size,
                              hipStream_t stream) {
    const float* x            = (const float*)d_in[0];
    const float* weight       = (const float*)d_in[1];
    const float* input_weight = (const float*)d_in[2];
    const float* bias         = (const float*)d_in[3];
    const float* tau          = (const float*)d_in[4];
    (void)in_sizes; (void)n_in; (void)out_size; (void)d_ws; (void)ws_size;

    rnn_kernel<<<256, 256, 0, stream>>>(x, weight, input_weight, bias, tau,
                                        (float*)d_out);
}